// Round 1
// baseline (978.174 us; speedup 1.0000x reference)
//
#include <hip/hip_runtime.h>

#define NN 50000
#define IN_DIM 128
#define HID 64
#define NLAYERS 3

__device__ __forceinline__ float lane_bcast(float v, int l) {
    return __uint_as_float(__builtin_amdgcn_readlane(__float_as_uint(v), l));
}

__global__ void k_zero(int* __restrict__ p, int n) {
    int i = blockIdx.x * blockDim.x + threadIdx.x;
    if (i < n) p[i] = 0;
}

__global__ void k_count(const int* __restrict__ dst, int* __restrict__ deg, int E) {
    int e = blockIdx.x * blockDim.x + threadIdx.x;
    if (e < E) atomicAdd(&deg[dst[e]], 1);
}

// 3-kernel exclusive scan over deg[N] -> off[N]
__global__ void k_scan_partial(const int* __restrict__ deg, int* __restrict__ part, int n) {
    __shared__ int s[256];
    int i = blockIdx.x * 256 + threadIdx.x;
    s[threadIdx.x] = (i < n) ? deg[i] : 0;
    __syncthreads();
    for (int d = 128; d > 0; d >>= 1) {
        if (threadIdx.x < d) s[threadIdx.x] += s[threadIdx.x + d];
        __syncthreads();
    }
    if (threadIdx.x == 0) part[blockIdx.x] = s[0];
}

__global__ void k_scan_root(int* part, int nb) {
    __shared__ int s[256];
    int t = threadIdx.x;
    int v = (t < nb) ? part[t] : 0;
    s[t] = v;
    __syncthreads();
    for (int d = 1; d < 256; d <<= 1) {
        int add = (t >= d) ? s[t - d] : 0;
        __syncthreads();
        s[t] += add;
        __syncthreads();
    }
    if (t < nb) part[t] = s[t] - v;  // exclusive prefix of block sums
}

__global__ void k_scan_final(const int* __restrict__ deg, const int* __restrict__ part,
                             int* __restrict__ off, int n) {
    __shared__ int s[256];
    int t = threadIdx.x;
    int i = blockIdx.x * 256 + t;
    int v = (i < n) ? deg[i] : 0;
    s[t] = v;
    __syncthreads();
    for (int d = 1; d < 256; d <<= 1) {
        int add = (t >= d) ? s[t - d] : 0;
        __syncthreads();
        s[t] += add;
        __syncthreads();
    }
    if (i < n) off[i] = part[blockIdx.x] + s[t] - v;
}

__global__ void k_scatter(const int* __restrict__ src, const int* __restrict__ dst,
                          const int* __restrict__ off, int* __restrict__ cursor,
                          int* __restrict__ csr, int E) {
    int e = blockIdx.x * blockDim.x + threadIdx.x;
    if (e < E) {
        int d = dst[e];
        int pos = atomicAdd(&cursor[d], 1);
        csr[off[d] + pos] = src[e];
    }
}

// h = x @ Wp + bp   (one wave per node, lane = output channel)
__global__ void k_proj(const float* __restrict__ x, const float* __restrict__ Wp,
                       const float* __restrict__ bp, float* __restrict__ h) {
    __shared__ float xs[4][IN_DIM];
    int lane = threadIdx.x & 63, wave = threadIdx.x >> 6;
    int node = blockIdx.x * 4 + wave;
    xs[wave][lane]      = x[node * IN_DIM + lane];
    xs[wave][64 + lane] = x[node * IN_DIM + 64 + lane];
    __syncthreads();
    float acc = bp[lane];
#pragma unroll
    for (int k = 0; k < IN_DIM; k += 4) {
        float4 xv = *(const float4*)&xs[wave][k];
        acc = fmaf(xv.x, Wp[(k + 0) * HID + lane], acc);
        acc = fmaf(xv.y, Wp[(k + 1) * HID + lane], acc);
        acc = fmaf(xv.z, Wp[(k + 2) * HID + lane], acc);
        acc = fmaf(xv.w, Wp[(k + 3) * HID + lane], acc);
    }
    h[node * HID + lane] = acc;
}

// P = h @ (W1top - W1bot) + b1 ; Q = h @ W1bot
__global__ void k_pq(const float* __restrict__ h, const float* __restrict__ W1,
                     const float* __restrict__ b1, float* __restrict__ P,
                     float* __restrict__ Q, int layer) {
    __shared__ float hs[4][HID];
    int lane = threadIdx.x & 63, wave = threadIdx.x >> 6;
    int node = blockIdx.x * 4 + wave;
    hs[wave][lane] = h[node * HID + lane];
    __syncthreads();
    const float* W1l = W1 + layer * 2 * HID * HID;
    float pacc = b1[layer * HID + lane], qacc = 0.f;
#pragma unroll
    for (int k = 0; k < HID; k += 4) {
        float4 hv = *(const float4*)&hs[wave][k];
        float hk[4] = {hv.x, hv.y, hv.z, hv.w};
#pragma unroll
        for (int i = 0; i < 4; i++) {
            float a = W1l[(k + i) * HID + lane];          // top half row
            float b = W1l[(HID + k + i) * HID + lane];    // bottom half row
            pacc = fmaf(hk[i], a - b, pacc);
            qacc = fmaf(hk[i], b, qacc);
        }
    }
    P[node * HID + lane] = pacc;
    Q[node * HID + lane] = qacc;
}

// Per dst node (one wave): max over incoming edges of relu(P[dst]+Q[src]) @ W2,
// then +b2, relu, +residual, in-place update of h.
__global__ void __launch_bounds__(256) k_edge(
    const float* __restrict__ P, const float* __restrict__ Q,
    const float* __restrict__ W2, const float* __restrict__ b2,
    const int* __restrict__ off, const int* __restrict__ deg,
    const int* __restrict__ csr, float* __restrict__ h, int layer) {
    int lane = threadIdx.x & 63, wave = threadIdx.x >> 6;
    int node = blockIdx.x * 4 + wave;
    const float* W2l = W2 + layer * HID * HID;
    float w2c[HID];  // column `lane` of W2 in registers
#pragma unroll
    for (int k = 0; k < HID; k++) w2c[k] = W2l[k * HID + lane];
    float p = P[node * HID + lane];
    int start = __builtin_amdgcn_readfirstlane(off[node]);
    int cnt   = __builtin_amdgcn_readfirstlane(deg[node]);
    float acc = -3.4e38f;
    for (int i = 0; i < cnt; i++) {
        int s = __builtin_amdgcn_readfirstlane(csr[start + i]);
        float q = Q[s * HID + lane];
        float r = fmaxf(p + q, 0.f);  // lane acts as k here
        float m = 0.f;
#pragma unroll
        for (int k = 0; k < HID; k++)
            m = fmaf(lane_bcast(r, k), w2c[k], m);  // lane acts as j here
        acc = fmaxf(acc, m);
    }
    float res = h[node * HID + lane];
    float out = (cnt > 0) ? fmaxf(acc + b2[layer * HID + lane], 0.f) : 0.f;
    h[node * HID + lane] = out + res;
}

// out = h @ Wo + bo  (wave reduction over 64 channels)
__global__ void k_out(const float* __restrict__ h, const float* __restrict__ Wo,
                      const float* __restrict__ bo, float* __restrict__ out) {
    int lane = threadIdx.x & 63, wave = threadIdx.x >> 6;
    int node = blockIdx.x * 4 + wave;
    float v = h[node * HID + lane] * Wo[lane];
#pragma unroll
    for (int m = 32; m >= 1; m >>= 1) v += __shfl_xor(v, m, 64);
    if (lane == 0) out[node] = v + bo[0];
}

extern "C" void kernel_launch(void* const* d_in, const int* in_sizes, int n_in,
                              void* d_out, int out_size, void* d_ws, size_t ws_size,
                              hipStream_t stream) {
    const float* x  = (const float*)d_in[0];
    const int*   ei = (const int*)d_in[1];
    const float* Wp = (const float*)d_in[2];
    const float* bp = (const float*)d_in[3];
    const float* W1 = (const float*)d_in[4];
    const float* b1 = (const float*)d_in[5];
    const float* W2 = (const float*)d_in[6];
    const float* b2 = (const float*)d_in[7];
    const float* Wo = (const float*)d_in[8];
    const float* bo = (const float*)d_in[9];
    float* out = (float*)d_out;

    const int E = in_sizes[1] / 2;
    const int N = NN;
    const int* srcp = ei;       // edge_index[0]
    const int* dstp = ei + E;   // edge_index[1]

    // workspace layout
    float* h  = (float*)d_ws;          // N*HID
    float* Pb = h + (size_t)N * HID;   // N*HID
    float* Qb = Pb + (size_t)N * HID;  // N*HID
    int* deg    = (int*)(Qb + (size_t)N * HID);  // N
    int* cursor = deg + N;                       // N (contiguous with deg for one zero-pass)
    int* off    = cursor + N;                    // N
    int* part   = off + N;                       // 256
    int* csr    = part + 256;                    // E

    int nbN = (N + 255) / 256;   // 196 (<=256 so single-block root scan works)
    int nbE = (E + 255) / 256;

    k_zero<<<(2 * N + 255) / 256, 256, 0, stream>>>(deg, 2 * N);
    k_count<<<nbE, 256, 0, stream>>>(dstp, deg, E);
    k_scan_partial<<<nbN, 256, 0, stream>>>(deg, part, N);
    k_scan_root<<<1, 256, 0, stream>>>(part, nbN);
    k_scan_final<<<nbN, 256, 0, stream>>>(deg, part, off, N);
    k_scatter<<<nbE, 256, 0, stream>>>(srcp, dstp, off, cursor, csr, E);

    k_proj<<<N / 4, 256, 0, stream>>>(x, Wp, bp, h);
    for (int l = 0; l < NLAYERS; l++) {
        k_pq<<<N / 4, 256, 0, stream>>>(h, W1, b1, Pb, Qb, l);
        k_edge<<<N / 4, 256, 0, stream>>>(Pb, Qb, W2, b2, off, deg, csr, h, l);
    }
    k_out<<<N / 4, 256, 0, stream>>>(h, Wo, bo, out);
}

// Round 2
// 518.553 us; speedup vs baseline: 1.8864x; 1.8864x over previous
//
#include <hip/hip_runtime.h>

#define NN 50000
#define IN_DIM 128
#define HID 64
#define NLAYERS 3

typedef __attribute__((ext_vector_type(8))) short bf16x8;
typedef __attribute__((ext_vector_type(4))) float f32x4;

__device__ __forceinline__ unsigned f2bf(float f) {
    unsigned u = __float_as_uint(f);
    return (u + 0x7fffu + ((u >> 16) & 1u)) >> 16;  // round-to-nearest-even
}

// q holds 2 packed bf16 (lo = element 2i, hi = 2i+1). Returns packed bf16 pair
// of relu(q + p).
__device__ __forceinline__ unsigned pack_r(unsigned q, float pA, float pB) {
    float lo = fmaxf(__uint_as_float(q << 16) + pA, 0.f);
    float hi = fmaxf(__uint_as_float(q & 0xffff0000u) + pB, 0.f);
    unsigned ul = f2bf(lo);
    unsigned uh = __float_as_uint(hi);
    uh = (uh + 0x7fffu + ((uh >> 16) & 1u)) & 0xffff0000u;
    return uh | ul;
}

__global__ void k_zero(int* __restrict__ p, int n) {
    int i = blockIdx.x * blockDim.x + threadIdx.x;
    if (i < n) p[i] = 0;
}

__global__ void k_count(const int* __restrict__ dst, int* __restrict__ deg, int E) {
    int e = blockIdx.x * blockDim.x + threadIdx.x;
    if (e < E) atomicAdd(&deg[dst[e]], 1);
}

__global__ void k_scan_partial(const int* __restrict__ deg, int* __restrict__ part, int n) {
    __shared__ int s[256];
    int i = blockIdx.x * 256 + threadIdx.x;
    s[threadIdx.x] = (i < n) ? deg[i] : 0;
    __syncthreads();
    for (int d = 128; d > 0; d >>= 1) {
        if (threadIdx.x < d) s[threadIdx.x] += s[threadIdx.x + d];
        __syncthreads();
    }
    if (threadIdx.x == 0) part[blockIdx.x] = s[0];
}

__global__ void k_scan_root(int* part, int nb) {
    __shared__ int s[256];
    int t = threadIdx.x;
    int v = (t < nb) ? part[t] : 0;
    s[t] = v;
    __syncthreads();
    for (int d = 1; d < 256; d <<= 1) {
        int add = (t >= d) ? s[t - d] : 0;
        __syncthreads();
        s[t] += add;
        __syncthreads();
    }
    if (t < nb) part[t] = s[t] - v;
}

__global__ void k_scan_final(const int* __restrict__ deg, const int* __restrict__ part,
                             int* __restrict__ off, int n) {
    __shared__ int s[256];
    int t = threadIdx.x;
    int i = blockIdx.x * 256 + t;
    int v = (i < n) ? deg[i] : 0;
    s[t] = v;
    __syncthreads();
    for (int d = 1; d < 256; d <<= 1) {
        int add = (t >= d) ? s[t - d] : 0;
        __syncthreads();
        s[t] += add;
        __syncthreads();
    }
    if (i < n) off[i] = part[blockIdx.x] + s[t] - v;
}

__global__ void k_scatter(const int* __restrict__ src, const int* __restrict__ dst,
                          const int* __restrict__ off, int* __restrict__ cursor,
                          int* __restrict__ csr, int E) {
    int e = blockIdx.x * blockDim.x + threadIdx.x;
    if (e < E) {
        int d = dst[e];
        int pos = atomicAdd(&cursor[d], 1);
        csr[off[d] + pos] = src[e];
    }
}

// h = x @ Wp + bp   (one wave per node, lane = output channel)
__global__ void k_proj(const float* __restrict__ x, const float* __restrict__ Wp,
                       const float* __restrict__ bp, float* __restrict__ h) {
    __shared__ float xs[4][IN_DIM];
    int lane = threadIdx.x & 63, wave = threadIdx.x >> 6;
    int node = blockIdx.x * 4 + wave;
    xs[wave][lane]      = x[node * IN_DIM + lane];
    xs[wave][64 + lane] = x[node * IN_DIM + 64 + lane];
    __syncthreads();
    float acc = bp[lane];
#pragma unroll
    for (int k = 0; k < IN_DIM; k += 4) {
        float4 xv = *(const float4*)&xs[wave][k];
        acc = fmaf(xv.x, Wp[(k + 0) * HID + lane], acc);
        acc = fmaf(xv.y, Wp[(k + 1) * HID + lane], acc);
        acc = fmaf(xv.z, Wp[(k + 2) * HID + lane], acc);
        acc = fmaf(xv.w, Wp[(k + 3) * HID + lane], acc);
    }
    h[node * HID + lane] = acc;
}

// P = h @ (W1top - W1bot) + b1 (fp32) ; Q = h @ W1bot (bf16)
__global__ void k_pq(const float* __restrict__ h, const float* __restrict__ W1,
                     const float* __restrict__ b1, float* __restrict__ P,
                     unsigned short* __restrict__ Qb, int layer) {
    __shared__ float hs[4][HID];
    int lane = threadIdx.x & 63, wave = threadIdx.x >> 6;
    int node = blockIdx.x * 4 + wave;
    hs[wave][lane] = h[node * HID + lane];
    __syncthreads();
    const float* W1l = W1 + layer * 2 * HID * HID;
    float pacc = b1[layer * HID + lane], qacc = 0.f;
#pragma unroll
    for (int k = 0; k < HID; k += 4) {
        float4 hv = *(const float4*)&hs[wave][k];
        float hk[4] = {hv.x, hv.y, hv.z, hv.w};
#pragma unroll
        for (int i = 0; i < 4; i++) {
            float a = W1l[(k + i) * HID + lane];
            float b = W1l[(HID + k + i) * HID + lane];
            pacc = fmaf(hk[i], a - b, pacc);
            qacc = fmaf(hk[i], b, qacc);
        }
    }
    P[node * HID + lane] = pacc;
    Qb[node * HID + lane] = (unsigned short)f2bf(qacc);
}

// One wave per dst node (grid-stride). 16 edges/batch through
// mfma_f32_16x16x32_bf16: C[edge, j] = relu(P[dst]+Q[src]) @ W2.
// Segment-max folded into C-layout running max; +b2, relu, +residual.
__global__ void __launch_bounds__(256) k_edge(
    const float* __restrict__ P, const unsigned short* __restrict__ Qb,
    const float* __restrict__ W2, const float* __restrict__ b2,
    const int* __restrict__ off, const int* __restrict__ deg,
    const int* __restrict__ csr, float* __restrict__ h, int layer, int nw) {
    int lane = threadIdx.x & 63;
    int col = lane & 15, quad = lane >> 4;
    int wid = (blockIdx.x * blockDim.x + threadIdx.x) >> 6;

    // B fragments: bfr[t][half][j] = W2[k = half*32 + quad*8 + j][t*16 + col]
    const float* W2l = W2 + layer * HID * HID;
    bf16x8 bfr[4][2];
#pragma unroll
    for (int t = 0; t < 4; t++)
#pragma unroll
        for (int hf = 0; hf < 2; hf++)
#pragma unroll
            for (int j = 0; j < 8; j++) {
                float w = W2l[(hf * 32 + quad * 8 + j) * HID + t * 16 + col];
                bfr[t][hf][j] = (short)f2bf(w);
            }
    float b2v = b2[layer * HID + lane];  // j = quad*16 + col == lane

    for (int node = wid; node < NN; node += nw) {
        int start = __builtin_amdgcn_readfirstlane(off[node]);
        int cnt   = __builtin_amdgcn_readfirstlane(deg[node]);
        float res = h[(size_t)node * HID + lane];
        float outv = 0.f;
        if (cnt > 0) {
            const float4* prow = (const float4*)(P + (size_t)node * HID);
            float4 pA = prow[quad * 2], pB = prow[quad * 2 + 1];
            float4 pC = prow[8 + quad * 2], pD = prow[8 + quad * 2 + 1];
            f32x4 mx[4];
#pragma unroll
            for (int t = 0; t < 4; t++) mx[t] = (f32x4)(-3.4e38f);
            for (int b0 = 0; b0 < cnt; b0 += 16) {
                int cb = cnt - b0; cb = cb < 16 ? cb : 16;
                int s = csr[start + b0 + (col < cb ? col : 0)];
                const uint4* qrow = (const uint4*)(Qb + (size_t)s * HID);
                uint4 q0 = qrow[quad];      // k in [quad*8, quad*8+8)
                uint4 q1 = qrow[4 + quad];  // k in [32+quad*8, ...)
                uint4 a0u, a1u;
                a0u.x = pack_r(q0.x, pA.x, pA.y);
                a0u.y = pack_r(q0.y, pA.z, pA.w);
                a0u.z = pack_r(q0.z, pB.x, pB.y);
                a0u.w = pack_r(q0.w, pB.z, pB.w);
                a1u.x = pack_r(q1.x, pC.x, pC.y);
                a1u.y = pack_r(q1.y, pC.z, pC.w);
                a1u.z = pack_r(q1.z, pD.x, pD.y);
                a1u.w = pack_r(q1.w, pD.z, pD.w);
                bf16x8 a0 = __builtin_bit_cast(bf16x8, a0u);
                bf16x8 a1 = __builtin_bit_cast(bf16x8, a1u);
#pragma unroll
                for (int t = 0; t < 4; t++) {
                    f32x4 c = __builtin_amdgcn_mfma_f32_16x16x32_bf16(
                        a0, bfr[t][0], (f32x4)(0.f), 0, 0, 0);
                    c = __builtin_amdgcn_mfma_f32_16x16x32_bf16(
                        a1, bfr[t][1], c, 0, 0, 0);
#pragma unroll
                    for (int r = 0; r < 4; r++) {
                        float cv = (quad * 4 + r) < cb ? c[r] : -3.4e38f;
                        mx[t][r] = fmaxf(mx[t][r], cv);
                    }
                }
            }
            float v[4];
#pragma unroll
            for (int t = 0; t < 4; t++) {
                v[t] = fmaxf(fmaxf(mx[t][0], mx[t][1]), fmaxf(mx[t][2], mx[t][3]));
                v[t] = fmaxf(v[t], __shfl_xor(v[t], 16, 64));
                v[t] = fmaxf(v[t], __shfl_xor(v[t], 32, 64));
            }
            float vs = quad == 0 ? v[0] : quad == 1 ? v[1] : quad == 2 ? v[2] : v[3];
            outv = fmaxf(vs + b2v, 0.f);
        }
        h[(size_t)node * HID + lane] = outv + res;
    }
}

// out = h @ Wo + bo  (wave reduction over 64 channels)
__global__ void k_out(const float* __restrict__ h, const float* __restrict__ Wo,
                      const float* __restrict__ bo, float* __restrict__ out) {
    int lane = threadIdx.x & 63, wave = threadIdx.x >> 6;
    int node = blockIdx.x * 4 + wave;
    float v = h[node * HID + lane] * Wo[lane];
#pragma unroll
    for (int m = 32; m >= 1; m >>= 1) v += __shfl_xor(v, m, 64);
    if (lane == 0) out[node] = v + bo[0];
}

extern "C" void kernel_launch(void* const* d_in, const int* in_sizes, int n_in,
                              void* d_out, int out_size, void* d_ws, size_t ws_size,
                              hipStream_t stream) {
    const float* x  = (const float*)d_in[0];
    const int*   ei = (const int*)d_in[1];
    const float* Wp = (const float*)d_in[2];
    const float* bp = (const float*)d_in[3];
    const float* W1 = (const float*)d_in[4];
    const float* b1 = (const float*)d_in[5];
    const float* W2 = (const float*)d_in[6];
    const float* b2 = (const float*)d_in[7];
    const float* Wo = (const float*)d_in[8];
    const float* bo = (const float*)d_in[9];
    float* out = (float*)d_out;

    const int E = in_sizes[1] / 2;
    const int N = NN;
    const int* srcp = ei;
    const int* dstp = ei + E;

    // workspace layout
    float* h  = (float*)d_ws;                       // N*HID f32
    float* Pb = h + (size_t)N * HID;                // N*HID f32
    unsigned short* Qb = (unsigned short*)(Pb + (size_t)N * HID);  // N*HID bf16
    int* deg    = (int*)(Qb + (size_t)N * HID);     // N
    int* cursor = deg + N;                          // N
    int* off    = cursor + N;                       // N
    int* part   = off + N;                          // 256
    int* csr    = part + 256;                       // E

    int nbN = (N + 255) / 256;
    int nbE = (E + 255) / 256;

    k_zero<<<(2 * N + 255) / 256, 256, 0, stream>>>(deg, 2 * N);
    k_count<<<nbE, 256, 0, stream>>>(dstp, deg, E);
    k_scan_partial<<<nbN, 256, 0, stream>>>(deg, part, N);
    k_scan_root<<<1, 256, 0, stream>>>(part, nbN);
    k_scan_final<<<nbN, 256, 0, stream>>>(deg, part, off, N);
    k_scatter<<<nbE, 256, 0, stream>>>(srcp, dstp, off, cursor, csr, E);

    k_proj<<<N / 4, 256, 0, stream>>>(x, Wp, bp, h);
    const int EDGE_BLOCKS = 1024;
    const int NW = EDGE_BLOCKS * 256 / 64;
    for (int l = 0; l < NLAYERS; l++) {
        k_pq<<<N / 4, 256, 0, stream>>>(h, W1, b1, Pb, Qb, l);
        k_edge<<<EDGE_BLOCKS, 256, 0, stream>>>(Pb, Qb, W2, b2, off, deg, csr, h, l, NW);
    }
    k_out<<<N / 4, 256, 0, stream>>>(h, Wo, bo, out);
}

// Round 3
// 398.586 us; speedup vs baseline: 2.4541x; 1.3010x over previous
//
#include <hip/hip_runtime.h>

#define NN 50000
#define IN_DIM 128
#define HID 64
#define NLAYERS 3

typedef __attribute__((ext_vector_type(8))) short bf16x8;
typedef __attribute__((ext_vector_type(4))) float f32x4;

__device__ __forceinline__ unsigned f2bf(float f) {
    unsigned u = __float_as_uint(f);
    return (u + 0x7fffu + ((u >> 16) & 1u)) >> 16;  // round-to-nearest-even
}

// q holds 2 packed bf16 (lo = element 2i, hi = 2i+1). Returns packed bf16 pair
// of relu(q + p).
__device__ __forceinline__ unsigned pack_r(unsigned q, float pA, float pB) {
    float lo = fmaxf(__uint_as_float(q << 16) + pA, 0.f);
    float hi = fmaxf(__uint_as_float(q & 0xffff0000u) + pB, 0.f);
    unsigned ul = f2bf(lo);
    unsigned uh = __float_as_uint(hi);
    uh = (uh + 0x7fffu + ((uh >> 16) & 1u)) & 0xffff0000u;
    return uh | ul;
}

__global__ void k_zero(int* __restrict__ p, int n) {
    int i = blockIdx.x * blockDim.x + threadIdx.x;
    if (i < n) p[i] = 0;
}

__global__ void k_count(const int* __restrict__ dst, int* __restrict__ deg, int E) {
    int e = blockIdx.x * blockDim.x + threadIdx.x;
    if (e < E) atomicAdd(&deg[dst[e]], 1);
}

__global__ void k_scan_partial(const int* __restrict__ deg, int* __restrict__ part, int n) {
    __shared__ int s[256];
    int i = blockIdx.x * 256 + threadIdx.x;
    s[threadIdx.x] = (i < n) ? deg[i] : 0;
    __syncthreads();
    for (int d = 128; d > 0; d >>= 1) {
        if (threadIdx.x < d) s[threadIdx.x] += s[threadIdx.x + d];
        __syncthreads();
    }
    if (threadIdx.x == 0) part[blockIdx.x] = s[0];
}

__global__ void k_scan_root(int* part, int nb) {
    __shared__ int s[256];
    int t = threadIdx.x;
    int v = (t < nb) ? part[t] : 0;
    s[t] = v;
    __syncthreads();
    for (int d = 1; d < 256; d <<= 1) {
        int add = (t >= d) ? s[t - d] : 0;
        __syncthreads();
        s[t] += add;
        __syncthreads();
    }
    if (t < nb) part[t] = s[t] - v;
}

__global__ void k_scan_final(const int* __restrict__ deg, const int* __restrict__ part,
                             int* __restrict__ off, int n) {
    __shared__ int s[256];
    int t = threadIdx.x;
    int i = blockIdx.x * 256 + t;
    int v = (i < n) ? deg[i] : 0;
    s[t] = v;
    __syncthreads();
    for (int d = 1; d < 256; d <<= 1) {
        int add = (t >= d) ? s[t - d] : 0;
        __syncthreads();
        s[t] += add;
        __syncthreads();
    }
    if (i < n) off[i] = part[blockIdx.x] + s[t] - v;
}

__global__ void k_scatter(const int* __restrict__ src, const int* __restrict__ dst,
                          const int* __restrict__ off, int* __restrict__ cursor,
                          int* __restrict__ csr, int E) {
    int e = blockIdx.x * blockDim.x + threadIdx.x;
    if (e < E) {
        int d = dst[e];
        int pos = atomicAdd(&cursor[d], 1);
        csr[off[d] + pos] = src[e];
    }
}

// h = x @ Wp + bp. Wave handles 4 nodes: weight loads amortized 4x, 4
// independent FMA chains hide load latency. Block = 16 nodes, 50000 = 3125*16.
__global__ void k_proj4(const float* __restrict__ x, const float* __restrict__ Wp,
                        const float* __restrict__ bp, float* __restrict__ h) {
    __shared__ float xs[4][4][IN_DIM];  // 8 KB
    int lane = threadIdx.x & 63, wave = threadIdx.x >> 6;
    int node0 = blockIdx.x * 16 + wave * 4;
#pragma unroll
    for (int n = 0; n < 4; n++) {
        xs[wave][n][lane]      = x[(size_t)(node0 + n) * IN_DIM + lane];
        xs[wave][n][64 + lane] = x[(size_t)(node0 + n) * IN_DIM + 64 + lane];
    }
    __syncthreads();
    float bv = bp[lane];
    float acc[4] = {bv, bv, bv, bv};
#pragma unroll
    for (int k = 0; k < IN_DIM; k += 4) {
        float w0 = Wp[(k + 0) * HID + lane];
        float w1 = Wp[(k + 1) * HID + lane];
        float w2 = Wp[(k + 2) * HID + lane];
        float w3 = Wp[(k + 3) * HID + lane];
#pragma unroll
        for (int n = 0; n < 4; n++) {
            float4 xv = *(const float4*)&xs[wave][n][k];
            acc[n] = fmaf(xv.x, w0, acc[n]);
            acc[n] = fmaf(xv.y, w1, acc[n]);
            acc[n] = fmaf(xv.z, w2, acc[n]);
            acc[n] = fmaf(xv.w, w3, acc[n]);
        }
    }
#pragma unroll
    for (int n = 0; n < 4; n++) h[(size_t)(node0 + n) * HID + lane] = acc[n];
}

// P = h @ (W1top - W1bot) + b1 (fp32) ; Q = h @ W1bot (bf16).
// Same 4-nodes-per-wave ILP structure as k_proj4.
__global__ void k_pq4(const float* __restrict__ h, const float* __restrict__ W1,
                      const float* __restrict__ b1, float* __restrict__ P,
                      unsigned short* __restrict__ Qb, int layer) {
    __shared__ float hs[4][4][HID];  // 4 KB
    int lane = threadIdx.x & 63, wave = threadIdx.x >> 6;
    int node0 = blockIdx.x * 16 + wave * 4;
#pragma unroll
    for (int n = 0; n < 4; n++)
        hs[wave][n][lane] = h[(size_t)(node0 + n) * HID + lane];
    __syncthreads();
    const float* W1l = W1 + layer * 2 * HID * HID;
    float bv = b1[layer * HID + lane];
    float pacc[4] = {bv, bv, bv, bv};
    float qacc[4] = {0.f, 0.f, 0.f, 0.f};
#pragma unroll
    for (int k = 0; k < HID; k += 4) {
        float a0 = W1l[(k + 0) * HID + lane], b0 = W1l[(HID + k + 0) * HID + lane];
        float a1 = W1l[(k + 1) * HID + lane], b1v = W1l[(HID + k + 1) * HID + lane];
        float a2 = W1l[(k + 2) * HID + lane], b2v = W1l[(HID + k + 2) * HID + lane];
        float a3 = W1l[(k + 3) * HID + lane], b3v = W1l[(HID + k + 3) * HID + lane];
        float d0 = a0 - b0, d1 = a1 - b1v, d2 = a2 - b2v, d3 = a3 - b3v;
#pragma unroll
        for (int n = 0; n < 4; n++) {
            float4 hv = *(const float4*)&hs[wave][n][k];
            pacc[n] = fmaf(hv.x, d0, pacc[n]);
            qacc[n] = fmaf(hv.x, b0, qacc[n]);
            pacc[n] = fmaf(hv.y, d1, pacc[n]);
            qacc[n] = fmaf(hv.y, b1v, qacc[n]);
            pacc[n] = fmaf(hv.z, d2, pacc[n]);
            qacc[n] = fmaf(hv.z, b2v, qacc[n]);
            pacc[n] = fmaf(hv.w, d3, pacc[n]);
            qacc[n] = fmaf(hv.w, b3v, qacc[n]);
        }
    }
#pragma unroll
    for (int n = 0; n < 4; n++) {
        P[(size_t)(node0 + n) * HID + lane] = pacc[n];
        Qb[(size_t)(node0 + n) * HID + lane] = (unsigned short)f2bf(qacc[n]);
    }
}

// One wave per dst node (grid-stride). 16 edges/batch through
// mfma_f32_16x16x32_bf16: C[edge, j] = relu(P[dst]+Q[src]) @ W2.
// Segment-max folded into C-layout running max; +b2, relu, +residual.
__global__ void __launch_bounds__(256) k_edge(
    const float* __restrict__ P, const unsigned short* __restrict__ Qb,
    const float* __restrict__ W2, const float* __restrict__ b2,
    const int* __restrict__ off, const int* __restrict__ deg,
    const int* __restrict__ csr, float* __restrict__ h, int layer, int nw) {
    int lane = threadIdx.x & 63;
    int col = lane & 15, quad = lane >> 4;
    int wid = (blockIdx.x * blockDim.x + threadIdx.x) >> 6;

    // B fragments: bfr[t][half][j] = W2[k = half*32 + quad*8 + j][t*16 + col]
    const float* W2l = W2 + layer * HID * HID;
    bf16x8 bfr[4][2];
#pragma unroll
    for (int t = 0; t < 4; t++)
#pragma unroll
        for (int hf = 0; hf < 2; hf++)
#pragma unroll
            for (int j = 0; j < 8; j++) {
                float w = W2l[(hf * 32 + quad * 8 + j) * HID + t * 16 + col];
                bfr[t][hf][j] = (short)f2bf(w);
            }
    float b2v = b2[layer * HID + lane];  // j = quad*16 + col == lane

    for (int node = wid; node < NN; node += nw) {
        int start = __builtin_amdgcn_readfirstlane(off[node]);
        int cnt   = __builtin_amdgcn_readfirstlane(deg[node]);
        float res = h[(size_t)node * HID + lane];
        float outv = 0.f;
        if (cnt > 0) {
            const float4* prow = (const float4*)(P + (size_t)node * HID);
            float4 pA = prow[quad * 2], pB = prow[quad * 2 + 1];
            float4 pC = prow[8 + quad * 2], pD = prow[8 + quad * 2 + 1];
            f32x4 mx[4];
#pragma unroll
            for (int t = 0; t < 4; t++) mx[t] = (f32x4)(-3.4e38f);
            for (int b0 = 0; b0 < cnt; b0 += 16) {
                int cb = cnt - b0; cb = cb < 16 ? cb : 16;
                int s = csr[start + b0 + (col < cb ? col : 0)];
                const uint4* qrow = (const uint4*)(Qb + (size_t)s * HID);
                uint4 q0 = qrow[quad];      // k in [quad*8, quad*8+8)
                uint4 q1 = qrow[4 + quad];  // k in [32+quad*8, ...)
                uint4 a0u, a1u;
                a0u.x = pack_r(q0.x, pA.x, pA.y);
                a0u.y = pack_r(q0.y, pA.z, pA.w);
                a0u.z = pack_r(q0.z, pB.x, pB.y);
                a0u.w = pack_r(q0.w, pB.z, pB.w);
                a1u.x = pack_r(q1.x, pC.x, pC.y);
                a1u.y = pack_r(q1.y, pC.z, pC.w);
                a1u.z = pack_r(q1.z, pD.x, pD.y);
                a1u.w = pack_r(q1.w, pD.z, pD.w);
                bf16x8 a0 = __builtin_bit_cast(bf16x8, a0u);
                bf16x8 a1 = __builtin_bit_cast(bf16x8, a1u);
#pragma unroll
                for (int t = 0; t < 4; t++) {
                    f32x4 c = __builtin_amdgcn_mfma_f32_16x16x32_bf16(
                        a0, bfr[t][0], (f32x4)(0.f), 0, 0, 0);
                    c = __builtin_amdgcn_mfma_f32_16x16x32_bf16(
                        a1, bfr[t][1], c, 0, 0, 0);
#pragma unroll
                    for (int r = 0; r < 4; r++) {
                        float cv = (quad * 4 + r) < cb ? c[r] : -3.4e38f;
                        mx[t][r] = fmaxf(mx[t][r], cv);
                    }
                }
            }
            float v[4];
#pragma unroll
            for (int t = 0; t < 4; t++) {
                v[t] = fmaxf(fmaxf(mx[t][0], mx[t][1]), fmaxf(mx[t][2], mx[t][3]));
                v[t] = fmaxf(v[t], __shfl_xor(v[t], 16, 64));
                v[t] = fmaxf(v[t], __shfl_xor(v[t], 32, 64));
            }
            float vs = quad == 0 ? v[0] : quad == 1 ? v[1] : quad == 2 ? v[2] : v[3];
            outv = fmaxf(vs + b2v, 0.f);
        }
        h[(size_t)node * HID + lane] = outv + res;
    }
}

// out = h @ Wo + bo  (wave reduction over 64 channels)
__global__ void k_out(const float* __restrict__ h, const float* __restrict__ Wo,
                      const float* __restrict__ bo, float* __restrict__ out) {
    int lane = threadIdx.x & 63, wave = threadIdx.x >> 6;
    int node = blockIdx.x * 4 + wave;
    float v = h[node * HID + lane] * Wo[lane];
#pragma unroll
    for (int m = 32; m >= 1; m >>= 1) v += __shfl_xor(v, m, 64);
    if (lane == 0) out[node] = v + bo[0];
}

extern "C" void kernel_launch(void* const* d_in, const int* in_sizes, int n_in,
                              void* d_out, int out_size, void* d_ws, size_t ws_size,
                              hipStream_t stream) {
    const float* x  = (const float*)d_in[0];
    const int*   ei = (const int*)d_in[1];
    const float* Wp = (const float*)d_in[2];
    const float* bp = (const float*)d_in[3];
    const float* W1 = (const float*)d_in[4];
    const float* b1 = (const float*)d_in[5];
    const float* W2 = (const float*)d_in[6];
    const float* b2 = (const float*)d_in[7];
    const float* Wo = (const float*)d_in[8];
    const float* bo = (const float*)d_in[9];
    float* out = (float*)d_out;

    const int E = in_sizes[1] / 2;
    const int N = NN;
    const int* srcp = ei;
    const int* dstp = ei + E;

    // workspace layout
    float* h  = (float*)d_ws;                       // N*HID f32
    float* Pb = h + (size_t)N * HID;                // N*HID f32
    unsigned short* Qb = (unsigned short*)(Pb + (size_t)N * HID);  // N*HID bf16
    int* deg    = (int*)(Qb + (size_t)N * HID);     // N
    int* cursor = deg + N;                          // N
    int* off    = cursor + N;                       // N
    int* part   = off + N;                          // 256
    int* csr    = part + 256;                       // E

    int nbN = (N + 255) / 256;
    int nbE = (E + 255) / 256;

    k_zero<<<(2 * N + 255) / 256, 256, 0, stream>>>(deg, 2 * N);
    k_count<<<nbE, 256, 0, stream>>>(dstp, deg, E);
    k_scan_partial<<<nbN, 256, 0, stream>>>(deg, part, N);
    k_scan_root<<<1, 256, 0, stream>>>(part, nbN);
    k_scan_final<<<nbN, 256, 0, stream>>>(deg, part, off, N);
    k_scatter<<<nbE, 256, 0, stream>>>(srcp, dstp, off, cursor, csr, E);

    k_proj4<<<N / 16, 256, 0, stream>>>(x, Wp, bp, h);
    const int EDGE_BLOCKS = 1024;
    const int NW = EDGE_BLOCKS * 256 / 64;
    for (int l = 0; l < NLAYERS; l++) {
        k_pq4<<<N / 16, 256, 0, stream>>>(h, W1, b1, Pb, Qb, l);
        k_edge<<<EDGE_BLOCKS, 256, 0, stream>>>(Pb, Qb, W2, b2, off, deg, csr, h, l, NW);
    }
    k_out<<<N / 4, 256, 0, stream>>>(h, Wo, bo, out);
}

// Round 4
// 373.477 us; speedup vs baseline: 2.6191x; 1.0672x over previous
//
#include <hip/hip_runtime.h>

#define NN 50000
#define IN_DIM 128
#define HID 64
#define NLAYERS 3

typedef __attribute__((ext_vector_type(8))) short bf16x8;
typedef __attribute__((ext_vector_type(4))) float f32x4;

__device__ __forceinline__ unsigned f2bf(float f) {
    unsigned u = __float_as_uint(f);
    return (u + 0x7fffu + ((u >> 16) & 1u)) >> 16;  // round-to-nearest-even
}

// Pack two fp32 -> packed bf16 pair (a -> lo, b -> hi), round-half-up (1.5 ulp worst).
__device__ __forceinline__ unsigned pk2bf(float a, float b) {
    return __builtin_amdgcn_perm(__float_as_uint(b) + 0x8000u,
                                 __float_as_uint(a) + 0x8000u, 0x07060302u);
}

// q = packed bf16 pair (lo = element 2i, hi = 2i+1). Returns packed bf16 pair
// of relu(q + p): 9 VALU ops.
__device__ __forceinline__ unsigned pack_r(unsigned q, float pA, float pB) {
    float lo = fmaxf(__uint_as_float(q << 16) + pA, 0.f);
    float hi = fmaxf(__uint_as_float(q & 0xffff0000u) + pB, 0.f);
    return pk2bf(lo, hi);
}

__global__ void k_zero(int* __restrict__ p, int n) {
    int i = blockIdx.x * blockDim.x + threadIdx.x;
    if (i < n) p[i] = 0;
}

__global__ void k_count(const int* __restrict__ dst, int* __restrict__ deg, int E) {
    int e = blockIdx.x * blockDim.x + threadIdx.x;
    if (e < E) atomicAdd(&deg[dst[e]], 1);
}

__global__ void k_scan_partial(const int* __restrict__ deg, int* __restrict__ part, int n) {
    __shared__ int s[256];
    int i = blockIdx.x * 256 + threadIdx.x;
    s[threadIdx.x] = (i < n) ? deg[i] : 0;
    __syncthreads();
    for (int d = 128; d > 0; d >>= 1) {
        if (threadIdx.x < d) s[threadIdx.x] += s[threadIdx.x + d];
        __syncthreads();
    }
    if (threadIdx.x == 0) part[blockIdx.x] = s[0];
}

__global__ void k_scan_root(int* part, int nb) {
    __shared__ int s[256];
    int t = threadIdx.x;
    int v = (t < nb) ? part[t] : 0;
    s[t] = v;
    __syncthreads();
    for (int d = 1; d < 256; d <<= 1) {
        int add = (t >= d) ? s[t - d] : 0;
        __syncthreads();
        s[t] += add;
        __syncthreads();
    }
    if (t < nb) part[t] = s[t] - v;
}

__global__ void k_scan_final(const int* __restrict__ deg, const int* __restrict__ part,
                             int* __restrict__ off, int n) {
    __shared__ int s[256];
    int t = threadIdx.x;
    int i = blockIdx.x * 256 + t;
    int v = (i < n) ? deg[i] : 0;
    s[t] = v;
    __syncthreads();
    for (int d = 1; d < 256; d <<= 1) {
        int add = (t >= d) ? s[t - d] : 0;
        __syncthreads();
        s[t] += add;
        __syncthreads();
    }
    if (i < n) off[i] = part[blockIdx.x] + s[t] - v;
}

__global__ void k_scatter(const int* __restrict__ src, const int* __restrict__ dst,
                          const int* __restrict__ off, int* __restrict__ cursor,
                          int* __restrict__ csr, int E) {
    int e = blockIdx.x * blockDim.x + threadIdx.x;
    if (e < E) {
        int d = dst[e];
        int pos = atomicAdd(&cursor[d], 1);
        csr[off[d] + pos] = src[e];
    }
}

// h = x @ Wp + bp. Wave handles 4 nodes: weight loads amortized 4x, 4
// independent FMA chains hide load latency. Block = 16 nodes, 50000 = 3125*16.
__global__ void k_proj4(const float* __restrict__ x, const float* __restrict__ Wp,
                        const float* __restrict__ bp, float* __restrict__ h) {
    __shared__ float xs[4][4][IN_DIM];  // 8 KB
    int lane = threadIdx.x & 63, wave = threadIdx.x >> 6;
    int node0 = blockIdx.x * 16 + wave * 4;
#pragma unroll
    for (int n = 0; n < 4; n++) {
        xs[wave][n][lane]      = x[(size_t)(node0 + n) * IN_DIM + lane];
        xs[wave][n][64 + lane] = x[(size_t)(node0 + n) * IN_DIM + 64 + lane];
    }
    __syncthreads();
    float bv = bp[lane];
    float acc[4] = {bv, bv, bv, bv};
#pragma unroll
    for (int k = 0; k < IN_DIM; k += 4) {
        float w0 = Wp[(k + 0) * HID + lane];
        float w1 = Wp[(k + 1) * HID + lane];
        float w2 = Wp[(k + 2) * HID + lane];
        float w3 = Wp[(k + 3) * HID + lane];
#pragma unroll
        for (int n = 0; n < 4; n++) {
            float4 xv = *(const float4*)&xs[wave][n][k];
            acc[n] = fmaf(xv.x, w0, acc[n]);
            acc[n] = fmaf(xv.y, w1, acc[n]);
            acc[n] = fmaf(xv.z, w2, acc[n]);
            acc[n] = fmaf(xv.w, w3, acc[n]);
        }
    }
#pragma unroll
    for (int n = 0; n < 4; n++) h[(size_t)(node0 + n) * HID + lane] = acc[n];
}

// [P|Q] = h @ [W1top-W1bot | W1bot] + [b1|0] via MFMA. One wave per 16 nodes.
// A: h rows (bf16), B: 8 n-tiles x 2 k-halves held in VGPRs (built once).
__global__ void __launch_bounds__(256) k_pq_mfma(
    const float* __restrict__ h, const float* __restrict__ W1,
    const float* __restrict__ b1, float* __restrict__ P,
    unsigned short* __restrict__ Qb, int layer) {
    int lane = threadIdx.x & 63, wave = threadIdx.x >> 6;
    int col = lane & 15, quad = lane >> 4;
    int node0 = (blockIdx.x * 4 + wave) * 16;
    if (node0 >= NN) return;
    const float* W1l = W1 + layer * 2 * HID * HID;

    // B fragments: bfr[t][hf][j] = W'[k = hf*32 + quad*8 + j][n], n = t*16+col
    // W' cols 0..63 = W1top - W1bot (P), 64..127 = W1bot (Q)
    bf16x8 bfr[8][2];
#pragma unroll
    for (int t = 0; t < 8; t++)
#pragma unroll
        for (int hf = 0; hf < 2; hf++) {
            uint4 u;
#pragma unroll
            for (int jp = 0; jp < 4; jp++) {
                int k0 = hf * 32 + quad * 8 + jp * 2;
                float w0, w1v;
                if (t < 4) {
                    int n = t * 16 + col;
                    w0  = W1l[k0 * HID + n] - W1l[(HID + k0) * HID + n];
                    w1v = W1l[(k0 + 1) * HID + n] - W1l[(HID + k0 + 1) * HID + n];
                } else {
                    int n = (t - 4) * 16 + col;
                    w0  = W1l[(HID + k0) * HID + n];
                    w1v = W1l[(HID + k0 + 1) * HID + n];
                }
                ((unsigned*)&u)[jp] = pk2bf(w0, w1v);
            }
            bfr[t][hf] = __builtin_bit_cast(bf16x8, u);
        }

    // A fragments: A[m=col][k=hf*32+quad*8+j] = h[node0+col][k]
    const float* hrow = h + (size_t)(node0 + col) * HID;
    float4 ha0 = *(const float4*)(hrow + quad * 8);
    float4 ha1 = *(const float4*)(hrow + quad * 8 + 4);
    float4 hb0 = *(const float4*)(hrow + 32 + quad * 8);
    float4 hb1 = *(const float4*)(hrow + 32 + quad * 8 + 4);
    uint4 au, bu;
    au.x = pk2bf(ha0.x, ha0.y); au.y = pk2bf(ha0.z, ha0.w);
    au.z = pk2bf(ha1.x, ha1.y); au.w = pk2bf(ha1.z, ha1.w);
    bu.x = pk2bf(hb0.x, hb0.y); bu.y = pk2bf(hb0.z, hb0.w);
    bu.z = pk2bf(hb1.x, hb1.y); bu.w = pk2bf(hb1.z, hb1.w);
    bf16x8 a0 = __builtin_bit_cast(bf16x8, au);
    bf16x8 a1 = __builtin_bit_cast(bf16x8, bu);

#pragma unroll
    for (int t = 0; t < 8; t++) {
        f32x4 c = __builtin_amdgcn_mfma_f32_16x16x32_bf16(a0, bfr[t][0], (f32x4)(0.f), 0, 0, 0);
        c = __builtin_amdgcn_mfma_f32_16x16x32_bf16(a1, bfr[t][1], c, 0, 0, 0);
        // C: row = quad*4 + r (node), col -> n = tile*16 + col
        if (t < 4) {
            float bv = b1[layer * HID + t * 16 + col];
#pragma unroll
            for (int r = 0; r < 4; r++)
                P[(size_t)(node0 + quad * 4 + r) * HID + t * 16 + col] = c[r] + bv;
        } else {
#pragma unroll
            for (int r = 0; r < 4; r++)
                Qb[(size_t)(node0 + quad * 4 + r) * HID + (t - 4) * 16 + col] =
                    (unsigned short)f2bf(c[r]);
        }
    }
}

// One wave per dst node (grid-stride). 16 edges/batch through
// mfma_f32_16x16x32_bf16: C[edge, j] = relu(P[dst]+Q[src]) @ W2.
// Pad lanes replicate edge b0 (valid) -> no tail masking needed for max.
__global__ void __launch_bounds__(256) k_edge(
    const float* __restrict__ P, const unsigned short* __restrict__ Qb,
    const float* __restrict__ W2, const float* __restrict__ b2,
    const int* __restrict__ off, const int* __restrict__ deg,
    const int* __restrict__ csr, float* __restrict__ h, int layer, int nw) {
    int lane = threadIdx.x & 63;
    int col = lane & 15, quad = lane >> 4;
    int wid = (blockIdx.x * blockDim.x + threadIdx.x) >> 6;

    // B fragments: bfr[t][half][j] = W2[k = half*32 + quad*8 + j][t*16 + col]
    const float* W2l = W2 + layer * HID * HID;
    bf16x8 bfr[4][2];
#pragma unroll
    for (int t = 0; t < 4; t++)
#pragma unroll
        for (int hf = 0; hf < 2; hf++) {
            uint4 u;
#pragma unroll
            for (int jp = 0; jp < 4; jp++) {
                int k0 = hf * 32 + quad * 8 + jp * 2;
                ((unsigned*)&u)[jp] = pk2bf(W2l[k0 * HID + t * 16 + col],
                                            W2l[(k0 + 1) * HID + t * 16 + col]);
            }
            bfr[t][hf] = __builtin_bit_cast(bf16x8, u);
        }
    float b2v = b2[layer * HID + lane];  // j = quad*16 + col == lane

    for (int node = wid; node < NN; node += nw) {
        int start = __builtin_amdgcn_readfirstlane(off[node]);
        int cnt   = __builtin_amdgcn_readfirstlane(deg[node]);
        float res = h[(size_t)node * HID + lane];
        float outv = 0.f;
        if (cnt > 0) {
            const float4* prow = (const float4*)(P + (size_t)node * HID);
            float4 pA = prow[quad * 2], pB = prow[quad * 2 + 1];
            float4 pC = prow[8 + quad * 2], pD = prow[8 + quad * 2 + 1];
            f32x4 mx[4];
#pragma unroll
            for (int t = 0; t < 4; t++) mx[t] = (f32x4)(-3.4e38f);
            for (int b0 = 0; b0 < cnt; b0 += 16) {
                int idx = b0 + col;
                int s = csr[start + (idx < cnt ? idx : b0)];
                const uint4* qrow = (const uint4*)(Qb + (size_t)s * HID);
                uint4 q0 = qrow[quad];      // k in [quad*8, quad*8+8)
                uint4 q1 = qrow[4 + quad];  // k in [32+quad*8, ...)
                uint4 a0u, a1u;
                a0u.x = pack_r(q0.x, pA.x, pA.y);
                a0u.y = pack_r(q0.y, pA.z, pA.w);
                a0u.z = pack_r(q0.z, pB.x, pB.y);
                a0u.w = pack_r(q0.w, pB.z, pB.w);
                a1u.x = pack_r(q1.x, pC.x, pC.y);
                a1u.y = pack_r(q1.y, pC.z, pC.w);
                a1u.z = pack_r(q1.z, pD.x, pD.y);
                a1u.w = pack_r(q1.w, pD.z, pD.w);
                bf16x8 a0 = __builtin_bit_cast(bf16x8, a0u);
                bf16x8 a1 = __builtin_bit_cast(bf16x8, a1u);
#pragma unroll
                for (int t = 0; t < 4; t++) {
                    f32x4 c = __builtin_amdgcn_mfma_f32_16x16x32_bf16(
                        a0, bfr[t][0], (f32x4)(0.f), 0, 0, 0);
                    c = __builtin_amdgcn_mfma_f32_16x16x32_bf16(
                        a1, bfr[t][1], c, 0, 0, 0);
#pragma unroll
                    for (int r = 0; r < 4; r++)
                        mx[t][r] = fmaxf(mx[t][r], c[r]);
                }
            }
            float v[4];
#pragma unroll
            for (int t = 0; t < 4; t++) {
                v[t] = fmaxf(fmaxf(mx[t][0], mx[t][1]), fmaxf(mx[t][2], mx[t][3]));
                v[t] = fmaxf(v[t], __shfl_xor(v[t], 16, 64));
                v[t] = fmaxf(v[t], __shfl_xor(v[t], 32, 64));
            }
            float vs = quad == 0 ? v[0] : quad == 1 ? v[1] : quad == 2 ? v[2] : v[3];
            outv = fmaxf(vs + b2v, 0.f);
        }
        h[(size_t)node * HID + lane] = outv + res;
    }
}

// out = h @ Wo + bo  (wave reduction over 64 channels)
__global__ void k_out(const float* __restrict__ h, const float* __restrict__ Wo,
                      const float* __restrict__ bo, float* __restrict__ out) {
    int lane = threadIdx.x & 63, wave = threadIdx.x >> 6;
    int node = blockIdx.x * 4 + wave;
    float v = h[node * HID + lane] * Wo[lane];
#pragma unroll
    for (int m = 32; m >= 1; m >>= 1) v += __shfl_xor(v, m, 64);
    if (lane == 0) out[node] = v + bo[0];
}

extern "C" void kernel_launch(void* const* d_in, const int* in_sizes, int n_in,
                              void* d_out, int out_size, void* d_ws, size_t ws_size,
                              hipStream_t stream) {
    const float* x  = (const float*)d_in[0];
    const int*   ei = (const int*)d_in[1];
    const float* Wp = (const float*)d_in[2];
    const float* bp = (const float*)d_in[3];
    const float* W1 = (const float*)d_in[4];
    const float* b1 = (const float*)d_in[5];
    const float* W2 = (const float*)d_in[6];
    const float* b2 = (const float*)d_in[7];
    const float* Wo = (const float*)d_in[8];
    const float* bo = (const float*)d_in[9];
    float* out = (float*)d_out;

    const int E = in_sizes[1] / 2;
    const int N = NN;
    const int* srcp = ei;
    const int* dstp = ei + E;

    // workspace layout
    float* h  = (float*)d_ws;                       // N*HID f32
    float* Pb = h + (size_t)N * HID;                // N*HID f32
    unsigned short* Qb = (unsigned short*)(Pb + (size_t)N * HID);  // N*HID bf16
    int* deg    = (int*)(Qb + (size_t)N * HID);     // N
    int* cursor = deg + N;                          // N
    int* off    = cursor + N;                       // N
    int* part   = off + N;                          // 256
    int* csr    = part + 256;                       // E

    int nbN = (N + 255) / 256;
    int nbE = (E + 255) / 256;

    k_zero<<<(2 * N + 255) / 256, 256, 0, stream>>>(deg, 2 * N);
    k_count<<<nbE, 256, 0, stream>>>(dstp, deg, E);
    k_scan_partial<<<nbN, 256, 0, stream>>>(deg, part, N);
    k_scan_root<<<1, 256, 0, stream>>>(part, nbN);
    k_scan_final<<<nbN, 256, 0, stream>>>(deg, part, off, N);
    k_scatter<<<nbE, 256, 0, stream>>>(srcp, dstp, off, cursor, csr, E);

    k_proj4<<<N / 16, 256, 0, stream>>>(x, Wp, bp, h);
    const int EDGE_BLOCKS = 2048;
    const int NW = EDGE_BLOCKS * 256 / 64;
    const int PQ_BLOCKS = (N / 16 + 3) / 4;  // 782
    for (int l = 0; l < NLAYERS; l++) {
        k_pq_mfma<<<PQ_BLOCKS, 256, 0, stream>>>(h, W1, b1, Pb, Qb, l);
        k_edge<<<EDGE_BLOCKS, 256, 0, stream>>>(Pb, Qb, W2, b2, off, deg, csr, h, l, NW);
    }
    k_out<<<N / 4, 256, 0, stream>>>(h, Wo, bo, out);
}